// Round 4
// baseline (504.090 us; speedup 1.0000x reference)
//
#include <hip/hip_runtime.h>
#include <hip/hip_bf16.h>
#include <stdint.h>

typedef __attribute__((ext_vector_type(8))) short short8;
typedef __attribute__((ext_vector_type(4))) float f32x4;
typedef __attribute__((ext_vector_type(4))) unsigned int u32x4;

#define NROWS 32768
#define DIM 512
#define KTOT 8192
#define KSPL 7680
#define LNEPS 1e-3f
// q = SQL * xn ; basis = exp2(-(q - SQL*grid_g)^2) ; SQL = 3.5*sqrt(log2(e))
#define SQL 4.20392843f

#if __has_builtin(__builtin_amdgcn_exp2f)
#define EXP2F(x) __builtin_amdgcn_exp2f(x)
#else
#define EXP2F(x) exp2f(x)
#endif

__device__ __forceinline__ unsigned short f2bf(float f) {
    unsigned u = __float_as_uint(f);
    u += 0x7fffu + ((u >> 16) & 1u);           // RNE
    return (unsigned short)(u >> 16);
}

// pack two floats -> two bf16 (round-half-up) in one u32 via v_perm
__device__ __forceinline__ unsigned pack_bf2(float a, float b) {
    unsigned ua = __float_as_uint(a) + 0x8000u;
    unsigned ub = __float_as_uint(b) + 0x8000u;
    return __builtin_amdgcn_perm(ub, ua, 0x07060302u); // lo16=ua>>16, hi16=ub>>16
}

// ---------------- prep: weights -> bf16 Bw[o][k], k = g*512+d (spline) | 7680+d (base^T)
// Coalesced global reads AND writes; transpose goes through LDS (stride-15
// float reads -> conflict-free on 32 banks).
__global__ __launch_bounds__(256) void prep_w_k(const float* __restrict__ sw,
                                                const float* __restrict__ bwt,
                                                unsigned short* __restrict__ Bw) {
    __shared__ float lds[KSPL];
    const int o = blockIdx.x;
    const int t = threadIdx.x;
    const float* swr = sw + (size_t)o * KSPL;
    unsigned short* br = Bw + (size_t)o * KTOT;
    #pragma unroll
    for (int it = 0; it < 30; ++it) lds[it * 256 + t] = swr[it * 256 + t];
    #pragma unroll
    for (int it = 0; it < 2; ++it) {
        int d = it * 256 + t;
        br[KSPL + d] = f2bf(bwt[(size_t)d * DIM + o]);
    }
    __syncthreads();
    #pragma unroll
    for (int it = 0; it < 30; ++it) {
        int k = it * 256 + t;              // destination order: k = g*512 + d
        int g = k >> 9, d = k & 511;
        br[k] = f2bf(lds[d * 15 + g]);
    }
}

// ---------------- fused LN + KAN GEMM, counted-vmcnt 2-phase pipeline (T3+T4).
// Block tile 128x512, 1024 thr (16 waves, wave tile 64x64). LDS 160KB:
// As double-buffered 2x16KB (full 64-k rows, 8-granule xor swizzle);
// Bs double-buffered, split by ks-half: [2 buf][2 ks][512 x 32k] 4x32KB
// (4-slot xor swizzle per half). Per step s, two phases (ks=0,1); each phase
// issues the half-tile DMA for step s+1 (consumed 2 phases later), does 16
// MFMAs on the current buffer, and ends with s_waitcnt vmcnt(2) + s_barrier
// (loads issued THIS phase stay in flight across the barrier). A-basis is
// generated in ph1, overlapping MFMA. Grid 256 = 1 block/CU.
__global__ __launch_bounds__(1024, 4) void kan_gemm(
    const float* __restrict__ x,
    const unsigned short* __restrict__ Bw,
    const float* __restrict__ gam,
    const float* __restrict__ bet,
    const float* __restrict__ bb,
    float* __restrict__ out) {
    __shared__ __align__(16) short As[2][128 * 64];      // 32 KB
    __shared__ __align__(16) short Bs[2][2][512 * 32];   // 128 KB

    const int t = threadIdx.x;
    const int w = t >> 6, l = t & 63;
    const int n0 = blockIdx.x << 7;

    const int ar  = t >> 3;    // A-staging row 0..127 (also LN-stats row)
    const int kkg = t & 7;     // A-staging k-granule
    const int wm = (w >> 3) << 6;            // wave row offset: 0 / 64
    const int wn = (w & 7) << 6;             // wave col offset: 0..448
    const int fm = l & 15, fq = l >> 4;
    const int asto = ((ar << 3) | (kkg ^ (ar & 7))) << 3;  // As store short-index

    // ---- B half-tile staging constants (per thread).
    // Half layout: row n (=out col) is 4 slots x 16B; slot s holds global
    // granule s ^ (n&3) (xor swizzle). DMA dest is wave-uniform + lane*16B,
    // so the swizzle is realized by permuting the per-lane GLOBAL source.
    const int rbA = w << 4;                  // rows 0..240 (16/wave)
    const int rbB = rbA + 256;               // rows 256..496
    const int slot = l & 3;
    const int nA = rbA + (l >> 2);
    const int nB = rbB + (l >> 2);
    const size_t srcA = (size_t)nA * KTOT + (size_t)((slot ^ (nA & 3)) << 3);
    const size_t srcB = (size_t)nB * KTOT + (size_t)((slot ^ (nB & 3)) << 3);

    // ---- LayerNorm stats for row ar (8 threads/row, shuffle reduce)
    const float* xrow = x + (size_t)(n0 + ar) * DIM;
    float s = 0.f, ss = 0.f;
    #pragma unroll
    for (int it = 0; it < 16; ++it) {
        float4 v = *(const float4*)(xrow + it * 32 + ((t & 7) << 2));
        s  += v.x + v.y + v.z + v.w;
        ss += v.x * v.x + v.y * v.y + v.z * v.z + v.w * v.w;
    }
    #pragma unroll
    for (int m = 4; m >= 1; m >>= 1) {
        s  += __shfl_xor(s,  m, 64);
        ss += __shfl_xor(ss, m, 64);
    }
    const float mean = s * (1.0f / DIM);
    const float rstd = rsqrtf(ss * (1.0f / DIM) - mean * mean + LNEPS);
    const float sr = SQL * rstd;

    f32x4 acc[4][4];
    #pragma unroll
    for (int i = 0; i < 4; ++i)
        #pragma unroll
        for (int j = 0; j < 4; ++j)
            acc[i][j] = (f32x4)0.0f;

    float xr[8], q[8];

    // load raw x slice (reused for relu) + q = SQL*layernorm(x) for d-block dn
    auto loadq = [&](int dn) {
        const int dc = (dn << 6) + (kkg << 3);
        float4 a = *(const float4*)(xrow + dc);
        float4 b = *(const float4*)(xrow + dc + 4);
        xr[0] = a.x; xr[1] = a.y; xr[2] = a.z; xr[3] = a.w;
        xr[4] = b.x; xr[5] = b.y; xr[6] = b.z; xr[7] = b.w;
        float4 g0 = *(const float4*)(gam + dc);
        float4 g1 = *(const float4*)(gam + dc + 4);
        float4 b0 = *(const float4*)(bet + dc);
        float4 b1 = *(const float4*)(bet + dc + 4);
        float gv[8] = {g0.x, g0.y, g0.z, g0.w, g1.x, g1.y, g1.z, g1.w};
        float bv[8] = {b0.x, b0.y, b0.z, b0.w, b1.x, b1.y, b1.z, b1.w};
        #pragma unroll
        for (int j = 0; j < 8; ++j) {
            float c = sr * gv[j];
            float o = __builtin_fmaf(-mean, c, SQL * bv[j]);
            q[j] = __builtin_fmaf(xr[j], c, o);
        }
    };

    // issue async DMA for one B half-tile (32KB, 2 gload_lds/thread)
    auto stageB = [&](int nb, int hs, int kcn) {
        const size_t kbase = (size_t)(kcn + (hs << 5));
        __builtin_amdgcn_global_load_lds(
            (const __attribute__((address_space(1))) void*)(Bw + srcA + kbase),
            (__attribute__((address_space(3))) void*)&Bs[nb][hs][rbA << 5],
            16, 0, 0);
        __builtin_amdgcn_global_load_lds(
            (const __attribute__((address_space(1))) void*)(Bw + srcB + kbase),
            (__attribute__((address_space(3))) void*)&Bs[nb][hs][rbB << 5],
            16, 0, 0);
    };

    // generate basis (or relu) granule gp -> bf16 -> As[nb] (xor-swizzled)
    auto stageA = [&](int nb, int gp) {
        u32x4 v;
        if (gp < 15) {
            const float qg = SQL * (-2.0f + (float)gp * (2.0f / 7.0f));
            float e[8];
            #pragma unroll
            for (int j = 0; j < 8; ++j) {
                float d = q[j] - qg;
                e[j] = EXP2F(-(d * d));
            }
            v[0] = pack_bf2(e[0], e[1]);
            v[1] = pack_bf2(e[2], e[3]);
            v[2] = pack_bf2(e[4], e[5]);
            v[3] = pack_bf2(e[6], e[7]);
        } else {
            v[0] = pack_bf2(fmaxf(xr[0], 0.f), fmaxf(xr[1], 0.f));
            v[1] = pack_bf2(fmaxf(xr[2], 0.f), fmaxf(xr[3], 0.f));
            v[2] = pack_bf2(fmaxf(xr[4], 0.f), fmaxf(xr[5], 0.f));
            v[3] = pack_bf2(fmaxf(xr[6], 0.f), fmaxf(xr[7], 0.f));
        }
        *(u32x4*)&As[nb][asto] = v;
    };

    // one ks-phase of MFMAs on buffer c
    auto mfma_phase = [&](int c, int ks) {
        const short* Asc = &As[c][0];
        const short* Bsc = &Bs[c][ks][0];
        const int kg = (ks << 2) + fq;
        short8 af[4], bfr[4];
        #pragma unroll
        for (int mt = 0; mt < 4; ++mt) {
            const int m = wm + (mt << 4) + fm;
            af[mt] = *(const short8*)&Asc[((m << 3) | (kg ^ (m & 7))) << 3];
        }
        #pragma unroll
        for (int nt = 0; nt < 4; ++nt) {
            const int n = wn + (nt << 4) + fm;
            bfr[nt] = *(const short8*)&Bsc[(n << 5) + ((fq ^ (n & 3)) << 3)];
        }
        __builtin_amdgcn_s_setprio(1);
        #pragma unroll
        for (int mt = 0; mt < 4; ++mt)
            #pragma unroll
            for (int nt = 0; nt < 4; ++nt)
                acc[mt][nt] = __builtin_amdgcn_mfma_f32_16x16x32_bf16(
                    af[mt], bfr[nt], acc[mt][nt], 0, 0, 0);
        __builtin_amdgcn_s_setprio(0);
    };

    // ---- prologue: stage step 0 fully into buffer 0, full drain once
    loadq(0);
    stageB(0, 0, 0);
    stageB(0, 1, 0);
    stageA(0, 0);
    asm volatile("s_waitcnt vmcnt(0) lgkmcnt(0)" ::: "memory");
    __builtin_amdgcn_s_barrier();

    // ---- main loop: steps 0..126 compute buf s&1, prefetch s+1 into s&1^1.
    // Loads issued in phase p are consumed in phase p+2; at each barrier the
    // 2 loads of THIS phase stay in flight (vmcnt(2)) -> no drain stall.
    #pragma unroll 1
    for (int sp = 0; sp < 127; ++sp) {
        const int c = sp & 1;
        const int snx = sp + 1;
        const int gq1 = snx & 15, d01 = (snx >> 4) << 6;
        const int kcn = (gq1 < 15) ? ((gq1 << 9) + d01) : (KSPL + d01);
        // -- ph0 (ks=0)
        if ((sp & 15) == 15) loadq(snx >> 4);   // new d-block q (8x per kernel)
        stageB(c ^ 1, 0, kcn);
        mfma_phase(c, 0);
        asm volatile("s_waitcnt vmcnt(2) lgkmcnt(0)" ::: "memory");
        __builtin_amdgcn_s_barrier();
        // -- ph1 (ks=1)
        stageB(c ^ 1, 1, kcn);
        mfma_phase(c, 1);
        stageA(c ^ 1, gq1);                      // VALU overlaps MFMA
        asm volatile("s_waitcnt vmcnt(2) lgkmcnt(0)" ::: "memory");
        __builtin_amdgcn_s_barrier();
    }
    // ---- peeled last step (s=127, c=1): no staging; drain the 2 ks1 loads
    mfma_phase(1, 0);
    asm volatile("s_waitcnt vmcnt(0) lgkmcnt(0)" ::: "memory");
    __builtin_amdgcn_s_barrier();
    mfma_phase(1, 1);

    // ---- epilogue: C layout col=lane&15, row=(lane>>4)*4+reg ; add base_b
    const int rq = fq << 2;
    float bias[4];
    #pragma unroll
    for (int nt = 0; nt < 4; ++nt) bias[nt] = bb[wn + (nt << 4) + fm];
    #pragma unroll
    for (int mt = 0; mt < 4; ++mt) {
        #pragma unroll
        for (int nt = 0; nt < 4; ++nt) {
            const int gr = n0 + wm + (mt << 4) + rq;
            const int gc = wn + (nt << 4) + fm;
            #pragma unroll
            for (int r = 0; r < 4; ++r)
                out[(size_t)(gr + r) * DIM + gc] = acc[mt][nt][r] + bias[nt];
        }
    }
}

extern "C" void kernel_launch(void* const* d_in, const int* in_sizes, int n_in,
                              void* d_out, int out_size, void* d_ws, size_t ws_size,
                              hipStream_t stream) {
    const float* x   = (const float*)d_in[0];
    const float* gam = (const float*)d_in[1];
    const float* bet = (const float*)d_in[2];
    const float* sw  = (const float*)d_in[3];
    const float* bwt = (const float*)d_in[4];
    const float* bb  = (const float*)d_in[5];
    float* out = (float*)d_out;

    unsigned short* Bw = (unsigned short*)d_ws;   // 512*8192 bf16 = 8 MB

    prep_w_k<<<dim3(512), dim3(256), 0, stream>>>(sw, bwt, Bw);
    kan_gemm<<<dim3(256), dim3(1024), 0, stream>>>(x, Bw, gam, bet, bb, out);
}